// Round 3
// baseline (2540.917 us; speedup 1.0000x reference)
//
#include <hip/hip_runtime.h>

#define NN 100000
#define NE 600000
#define DD 128

// ---------------------------------------------------------------------------
// Kernel 1: hbuf[n][d] = (1+eps) * x[n][d]   (also zero-inits the scatter
// target, since ws is re-poisoned to 0xAA before every timed launch)
// ---------------------------------------------------------------------------
__global__ __launch_bounds__(256) void init_kernel(const float* __restrict__ x,
                                                   const float* __restrict__ eps_p,
                                                   float* __restrict__ hbuf) {
    const int i = blockIdx.x * 256 + threadIdx.x;  // float4 index
    const float s = 1.0f + eps_p[0];
    if (i < NN * DD / 4) {
        float4 v = reinterpret_cast<const float4*>(x)[i];
        v.x *= s; v.y *= s; v.z *= s; v.w *= s;
        reinterpret_cast<float4*>(hbuf)[i] = v;
    }
}

// ---------------------------------------------------------------------------
// Kernel 2: per edge e=(u,v):
//   hbuf[u] += relu(x[v] + ea[e]);  hbuf[v] += relu(x[u] + ea[e])
// 32 lanes per edge, float4 per lane, 8 fp32 HW atomics per lane.
// unsafeAtomicAdd: guarantees global_atomic_add_f32 (plain atomicAdd(float*)
// may lower to a CAS loop without -munsafe-fp-atomics).
// ---------------------------------------------------------------------------
__global__ __launch_bounds__(256) void edge_kernel(const float* __restrict__ x,
                                                   const float* __restrict__ ea,
                                                   const int* __restrict__ ei,
                                                   float* __restrict__ hbuf) {
    const int e = blockIdx.x * 8 + (threadIdx.x >> 5);
    if (e >= NE) return;
    const int t = threadIdx.x & 31;
    const int u = ei[e];
    const int v = ei[NE + e];

    const float4 a  = reinterpret_cast<const float4*>(ea)[(size_t)e * 32 + t];
    const float4 xu = reinterpret_cast<const float4*>(x)[(size_t)u * 32 + t];
    const float4 xv = reinterpret_cast<const float4*>(x)[(size_t)v * 32 + t];

    float4 mu, mv;  // message to u uses x[v]; message to v uses x[u]
    mu.x = fmaxf(xv.x + a.x, 0.0f);
    mu.y = fmaxf(xv.y + a.y, 0.0f);
    mu.z = fmaxf(xv.z + a.z, 0.0f);
    mu.w = fmaxf(xv.w + a.w, 0.0f);
    mv.x = fmaxf(xu.x + a.x, 0.0f);
    mv.y = fmaxf(xu.y + a.y, 0.0f);
    mv.z = fmaxf(xu.z + a.z, 0.0f);
    mv.w = fmaxf(xu.w + a.w, 0.0f);

    float* du = hbuf + (size_t)u * DD + t * 4;
    float* dv = hbuf + (size_t)v * DD + t * 4;
    unsafeAtomicAdd(du + 0, mu.x);
    unsafeAtomicAdd(du + 1, mu.y);
    unsafeAtomicAdd(du + 2, mu.z);
    unsafeAtomicAdd(du + 3, mu.w);
    unsafeAtomicAdd(dv + 0, mv.x);
    unsafeAtomicAdd(dv + 1, mv.y);
    unsafeAtomicAdd(dv + 2, mv.z);
    unsafeAtomicAdd(dv + 3, mv.w);
}

// ---------------------------------------------------------------------------
// Kernels 3/4: out[n] = act(in[n] @ W + b), W is 128x128 fp32 (64 KB in LDS).
// 256 threads = 8 groups of 32 lanes; each group computes FOUR nodes
// (register blocking: 4x float4 acc per lane) so W is read from LDS once per
// 4 nodes, not once per node (4x LDS traffic cut -> VALU-issue-bound).
// h rows staged in LDS; group reads them via broadcast ds_read_b128.
// 32 nodes/block -> 3125 blocks exactly (100000 = 3125*32), no tail.
// ---------------------------------------------------------------------------
template <int RELU>
__global__ __launch_bounds__(256) void mlp_kernel(const float* __restrict__ in,
                                                  const float* __restrict__ W,
                                                  const float* __restrict__ bias,
                                                  float* __restrict__ out) {
    __shared__ float Wl[DD * DD];    // 64 KB
    __shared__ float hl[32 * DD];    // 16 KB
    const int tid = threadIdx.x;
    float4* Wl4 = reinterpret_cast<float4*>(Wl);
    const float4* W4 = reinterpret_cast<const float4*>(W);
#pragma unroll
    for (int i = 0; i < 16; ++i) Wl4[i * 256 + tid] = W4[i * 256 + tid];

    const int base = blockIdx.x * 32;  // first node of this block
    float4* hl4 = reinterpret_cast<float4*>(hl);
    const float4* in4 = reinterpret_cast<const float4*>(in);
#pragma unroll
    for (int i = 0; i < 4; ++i)
        hl4[i * 256 + tid] = in4[(size_t)base * 32 + i * 256 + tid];
    __syncthreads();

    const int g = tid >> 5;  // group 0..7 -> local nodes 4g..4g+3
    const int t = tid & 31;  // lane -> output columns 4t..4t+3
    const float4* h0 = reinterpret_cast<const float4*>(hl + (4 * g + 0) * DD);
    const float4* h1 = reinterpret_cast<const float4*>(hl + (4 * g + 1) * DD);
    const float4* h2 = reinterpret_cast<const float4*>(hl + (4 * g + 2) * DD);
    const float4* h3 = reinterpret_cast<const float4*>(hl + (4 * g + 3) * DD);

    float4 acc0 = {0, 0, 0, 0}, acc1 = {0, 0, 0, 0};
    float4 acc2 = {0, 0, 0, 0}, acc3 = {0, 0, 0, 0};

#pragma unroll 8
    for (int kq = 0; kq < 32; ++kq) {  // k-quad: k = 4*kq .. 4*kq+3
        const float4 ha = h0[kq];
        const float4 hb = h1[kq];
        const float4 hc = h2[kq];
        const float4 hd = h3[kq];
        const float4 w0 = Wl4[(4 * kq + 0) * 32 + t];
        const float4 w1 = Wl4[(4 * kq + 1) * 32 + t];
        const float4 w2 = Wl4[(4 * kq + 2) * 32 + t];
        const float4 w3 = Wl4[(4 * kq + 3) * 32 + t];

#define ACC_STEP(A, H)                                    \
        A.x = fmaf(H.x, w0.x, A.x);                       \
        A.y = fmaf(H.x, w0.y, A.y);                       \
        A.z = fmaf(H.x, w0.z, A.z);                       \
        A.w = fmaf(H.x, w0.w, A.w);                       \
        A.x = fmaf(H.y, w1.x, A.x);                       \
        A.y = fmaf(H.y, w1.y, A.y);                       \
        A.z = fmaf(H.y, w1.z, A.z);                       \
        A.w = fmaf(H.y, w1.w, A.w);                       \
        A.x = fmaf(H.z, w2.x, A.x);                       \
        A.y = fmaf(H.z, w2.y, A.y);                       \
        A.z = fmaf(H.z, w2.z, A.z);                       \
        A.w = fmaf(H.z, w2.w, A.w);                       \
        A.x = fmaf(H.w, w3.x, A.x);                       \
        A.y = fmaf(H.w, w3.y, A.y);                       \
        A.z = fmaf(H.w, w3.z, A.z);                       \
        A.w = fmaf(H.w, w3.w, A.w);
        ACC_STEP(acc0, ha)
        ACC_STEP(acc1, hb)
        ACC_STEP(acc2, hc)
        ACC_STEP(acc3, hd)
#undef ACC_STEP
    }

    const float4 bb = reinterpret_cast<const float4*>(bias)[t];
    acc0.x += bb.x; acc0.y += bb.y; acc0.z += bb.z; acc0.w += bb.w;
    acc1.x += bb.x; acc1.y += bb.y; acc1.z += bb.z; acc1.w += bb.w;
    acc2.x += bb.x; acc2.y += bb.y; acc2.z += bb.z; acc2.w += bb.w;
    acc3.x += bb.x; acc3.y += bb.y; acc3.z += bb.z; acc3.w += bb.w;
    if (RELU) {
        acc0.x = fmaxf(acc0.x, 0.0f); acc0.y = fmaxf(acc0.y, 0.0f);
        acc0.z = fmaxf(acc0.z, 0.0f); acc0.w = fmaxf(acc0.w, 0.0f);
        acc1.x = fmaxf(acc1.x, 0.0f); acc1.y = fmaxf(acc1.y, 0.0f);
        acc1.z = fmaxf(acc1.z, 0.0f); acc1.w = fmaxf(acc1.w, 0.0f);
        acc2.x = fmaxf(acc2.x, 0.0f); acc2.y = fmaxf(acc2.y, 0.0f);
        acc2.z = fmaxf(acc2.z, 0.0f); acc2.w = fmaxf(acc2.w, 0.0f);
        acc3.x = fmaxf(acc3.x, 0.0f); acc3.y = fmaxf(acc3.y, 0.0f);
        acc3.z = fmaxf(acc3.z, 0.0f); acc3.w = fmaxf(acc3.w, 0.0f);
    }

    float4* out4 = reinterpret_cast<float4*>(out);
    const size_t n0 = (size_t)(base + 4 * g) * 32 + t;
    out4[n0 + 0 * 32] = acc0;
    out4[n0 + 1 * 32] = acc1;
    out4[n0 + 2 * 32] = acc2;
    out4[n0 + 3 * 32] = acc3;
}

extern "C" void kernel_launch(void* const* d_in, const int* in_sizes, int n_in,
                              void* d_out, int out_size, void* d_ws, size_t ws_size,
                              hipStream_t stream) {
    const float* x    = (const float*)d_in[0];
    const float* ea   = (const float*)d_in[1];
    const float* W1   = (const float*)d_in[2];
    const float* b1   = (const float*)d_in[3];
    const float* W2   = (const float*)d_in[4];
    const float* b2   = (const float*)d_in[5];
    const float* eps  = (const float*)d_in[6];
    const int*   ei   = (const int*)d_in[7];
    float* out  = (float*)d_out;
    float* hbuf = (float*)d_ws;  // N*D fp32 = 51.2 MB scratch

    // 1) hbuf = (1+eps)*x
    init_kernel<<<NN * DD / 4 / 256, 256, 0, stream>>>(x, eps, hbuf);
    // 2) scatter edge messages into hbuf (HW fp32 atomics)
    edge_kernel<<<NE / 8, 256, 0, stream>>>(x, ea, ei, hbuf);
    // 3) h1 = relu(hbuf @ W1 + b1) -> stored in d_out (reused as scratch)
    mlp_kernel<1><<<NN / 32, 256, 0, stream>>>(hbuf, W1, b1, out);
    // 4) out = h1 @ W2 + b2 (in-place: rows are register/LDS-buffered per block)
    mlp_kernel<0><<<NN / 32, 256, 0, stream>>>(out, W2, b2, out);
}

// Round 4
// 893.689 us; speedup vs baseline: 2.8432x; 2.8432x over previous
//
#include <hip/hip_runtime.h>

#define NN 100000
#define NE 600000
#define DD 128

// ws layout (int offsets from base):
//   deg     [100352]  (padded to 392*256... actually 391*256=100096, pad 100352)
//   partials[512]
//   offs    [100352]  (needs NN+1)
//   cursor  [100352]
//   entries [2*NE = 1200000]
#define WS_DEG      0
#define WS_PARTIALS 100352
#define WS_OFFS     100864
#define WS_CURSOR   201216
#define WS_ENTRIES  301568
#define ZERO_INTS   100864   // deg + partials zeroed每 launch (ws is re-poisoned)

// ---------------------------------------------------------------------------
__global__ __launch_bounds__(256) void zero_kernel(int* __restrict__ w) {
    const int i = blockIdx.x * 256 + threadIdx.x;
    if (i < ZERO_INTS) w[i] = 0;
}

// deg[n] = number of incident edge-endpoints (counts both directions)
__global__ __launch_bounds__(256) void hist_kernel(const int* __restrict__ ei,
                                                   int* __restrict__ deg) {
    const int e = blockIdx.x * 256 + threadIdx.x;
    if (e >= NE) return;
    atomicAdd(&deg[ei[e]], 1);
    atomicAdd(&deg[ei[NE + e]], 1);
}

// Per-block exclusive scan of deg -> offs; block sums -> partials. 391 blocks.
__global__ __launch_bounds__(256) void scan1_kernel(const int* __restrict__ deg,
                                                    int* __restrict__ offs,
                                                    int* __restrict__ partials) {
    __shared__ int s[256];
    const int tid = threadIdx.x;
    const int i = blockIdx.x * 256 + tid;
    const int v = deg[i];  // padded region is zeroed
    s[tid] = v;
    __syncthreads();
#pragma unroll
    for (int d = 1; d < 256; d <<= 1) {
        const int t = (tid >= d) ? s[tid - d] : 0;
        __syncthreads();
        s[tid] += t;
        __syncthreads();
    }
    offs[i] = s[tid] - v;  // exclusive within block
    if (tid == 255) partials[blockIdx.x] = s[255];
}

// Exclusive scan of 391 partials in one block of 512.
__global__ __launch_bounds__(512) void scan2_kernel(int* __restrict__ partials) {
    __shared__ int s[512];
    const int tid = threadIdx.x;
    const int v = (tid < 391) ? partials[tid] : 0;
    s[tid] = v;
    __syncthreads();
#pragma unroll
    for (int d = 1; d < 512; d <<= 1) {
        const int t = (tid >= d) ? s[tid - d] : 0;
        __syncthreads();
        s[tid] += t;
        __syncthreads();
    }
    if (tid < 391) partials[tid] = s[tid] - v;
    __syncthreads();
}

// offs[i] += partials[i>>8]; cursor[i] = offs[i].  Valid for i <= NN
// (i==NN lands in block 390's zero-padded tail, yielding total 2*NE).
__global__ __launch_bounds__(256) void finalize_kernel(int* __restrict__ offs,
                                                       const int* __restrict__ partials,
                                                       int* __restrict__ cursor) {
    const int i = blockIdx.x * 256 + threadIdx.x;
    if (i > NN) return;
    const int r = offs[i] + partials[i >> 8];
    offs[i] = r;
    if (i < NN) cursor[i] = r;
}

// entries[pos] = (e<<1) | dir.  dir=0: message to u (uses x[v]); dir=1: to v.
__global__ __launch_bounds__(256) void fill_kernel(const int* __restrict__ ei,
                                                   int* __restrict__ cursor,
                                                   int* __restrict__ entries) {
    const int e = blockIdx.x * 256 + threadIdx.x;
    if (e >= NE) return;
    const int u = ei[e];
    const int v = ei[NE + e];
    const int p1 = atomicAdd(&cursor[u], 1);
    entries[p1] = (e << 1);
    const int p2 = atomicAdd(&cursor[v], 1);
    entries[p2] = (e << 1) | 1;
}

// d_out[n][d] = (1+eps) * x[n][d]
__global__ __launch_bounds__(256) void init_kernel(const float* __restrict__ x,
                                                   const float* __restrict__ eps_p,
                                                   float* __restrict__ out) {
    const int i = blockIdx.x * 256 + threadIdx.x;  // float4 index, 12500 blocks exact
    const float s = 1.0f + eps_p[0];
    float4 v = reinterpret_cast<const float4*>(x)[i];
    v.x *= s; v.y *= s; v.z *= s; v.w *= s;
    reinterpret_cast<float4*>(out)[i] = v;
}

// One 32-lane group per node: accumulate relu(x[other]+ea[e]) over incident
// edges in registers, then out[n] += acc (in place; row owned by this group).
__global__ __launch_bounds__(256) void gather_kernel(const float* __restrict__ x,
                                                     const float* __restrict__ ea,
                                                     const int* __restrict__ ei,
                                                     const int* __restrict__ offs,
                                                     const int* __restrict__ entries,
                                                     float* __restrict__ out) {
    const int node = blockIdx.x * 8 + (threadIdx.x >> 5);  // 12500 blocks exact
    const int t = threadIdx.x & 31;
    const int start = offs[node];
    const int end = offs[node + 1];
    const float4* x4 = reinterpret_cast<const float4*>(x);
    const float4* ea4 = reinterpret_cast<const float4*>(ea);
    float4 acc = {0.0f, 0.0f, 0.0f, 0.0f};
    for (int j = start; j < end; ++j) {
        const int entry = entries[j];
        const int e = entry >> 1;
        const int other = (entry & 1) ? ei[e] : ei[NE + e];
        const float4 a = ea4[(size_t)e * 32 + t];
        const float4 xo = x4[(size_t)other * 32 + t];
        acc.x += fmaxf(xo.x + a.x, 0.0f);
        acc.y += fmaxf(xo.y + a.y, 0.0f);
        acc.z += fmaxf(xo.z + a.z, 0.0f);
        acc.w += fmaxf(xo.w + a.w, 0.0f);
    }
    float4* out4 = reinterpret_cast<float4*>(out);
    const size_t oi = (size_t)node * 32 + t;
    float4 o = out4[oi];
    o.x += acc.x; o.y += acc.y; o.z += acc.z; o.w += acc.w;
    out4[oi] = o;
}

// ---------------------------------------------------------------------------
// MLP: out[n] = act(in[n] @ W + b), W 128x128 fp32 in LDS (64 KB).
// 8 groups of 32 lanes; each group computes 4 nodes (4x float4 acc/lane).
// In-place safe: block stages its 32 rows into LDS before any write.
// ---------------------------------------------------------------------------
template <int RELU>
__global__ __launch_bounds__(256) void mlp_kernel(const float* __restrict__ in,
                                                  const float* __restrict__ W,
                                                  const float* __restrict__ bias,
                                                  float* __restrict__ out) {
    __shared__ float Wl[DD * DD];    // 64 KB
    __shared__ float hl[32 * DD];    // 16 KB
    const int tid = threadIdx.x;
    float4* Wl4 = reinterpret_cast<float4*>(Wl);
    const float4* W4 = reinterpret_cast<const float4*>(W);
#pragma unroll
    for (int i = 0; i < 16; ++i) Wl4[i * 256 + tid] = W4[i * 256 + tid];

    const int base = blockIdx.x * 32;  // 3125 blocks exact
    float4* hl4 = reinterpret_cast<float4*>(hl);
    const float4* in4 = reinterpret_cast<const float4*>(in);
#pragma unroll
    for (int i = 0; i < 4; ++i)
        hl4[i * 256 + tid] = in4[(size_t)base * 32 + i * 256 + tid];
    __syncthreads();

    const int g = tid >> 5;
    const int t = tid & 31;
    const float4* h0 = reinterpret_cast<const float4*>(hl + (4 * g + 0) * DD);
    const float4* h1 = reinterpret_cast<const float4*>(hl + (4 * g + 1) * DD);
    const float4* h2 = reinterpret_cast<const float4*>(hl + (4 * g + 2) * DD);
    const float4* h3 = reinterpret_cast<const float4*>(hl + (4 * g + 3) * DD);

    float4 acc0 = {0, 0, 0, 0}, acc1 = {0, 0, 0, 0};
    float4 acc2 = {0, 0, 0, 0}, acc3 = {0, 0, 0, 0};

#pragma unroll 8
    for (int kq = 0; kq < 32; ++kq) {
        const float4 ha = h0[kq];
        const float4 hb = h1[kq];
        const float4 hc = h2[kq];
        const float4 hd = h3[kq];
        const float4 w0 = Wl4[(4 * kq + 0) * 32 + t];
        const float4 w1 = Wl4[(4 * kq + 1) * 32 + t];
        const float4 w2 = Wl4[(4 * kq + 2) * 32 + t];
        const float4 w3 = Wl4[(4 * kq + 3) * 32 + t];

#define ACC_STEP(A, H)                                    \
        A.x = fmaf(H.x, w0.x, A.x);                       \
        A.y = fmaf(H.x, w0.y, A.y);                       \
        A.z = fmaf(H.x, w0.z, A.z);                       \
        A.w = fmaf(H.x, w0.w, A.w);                       \
        A.x = fmaf(H.y, w1.x, A.x);                       \
        A.y = fmaf(H.y, w1.y, A.y);                       \
        A.z = fmaf(H.y, w1.z, A.z);                       \
        A.w = fmaf(H.y, w1.w, A.w);                       \
        A.x = fmaf(H.z, w2.x, A.x);                       \
        A.y = fmaf(H.z, w2.y, A.y);                       \
        A.z = fmaf(H.z, w2.z, A.z);                       \
        A.w = fmaf(H.z, w2.w, A.w);                       \
        A.x = fmaf(H.w, w3.x, A.x);                       \
        A.y = fmaf(H.w, w3.y, A.y);                       \
        A.z = fmaf(H.w, w3.z, A.z);                       \
        A.w = fmaf(H.w, w3.w, A.w);
        ACC_STEP(acc0, ha)
        ACC_STEP(acc1, hb)
        ACC_STEP(acc2, hc)
        ACC_STEP(acc3, hd)
#undef ACC_STEP
    }

    const float4 bb = reinterpret_cast<const float4*>(bias)[t];
    acc0.x += bb.x; acc0.y += bb.y; acc0.z += bb.z; acc0.w += bb.w;
    acc1.x += bb.x; acc1.y += bb.y; acc1.z += bb.z; acc1.w += bb.w;
    acc2.x += bb.x; acc2.y += bb.y; acc2.z += bb.z; acc2.w += bb.w;
    acc3.x += bb.x; acc3.y += bb.y; acc3.z += bb.z; acc3.w += bb.w;
    if (RELU) {
        acc0.x = fmaxf(acc0.x, 0.0f); acc0.y = fmaxf(acc0.y, 0.0f);
        acc0.z = fmaxf(acc0.z, 0.0f); acc0.w = fmaxf(acc0.w, 0.0f);
        acc1.x = fmaxf(acc1.x, 0.0f); acc1.y = fmaxf(acc1.y, 0.0f);
        acc1.z = fmaxf(acc1.z, 0.0f); acc1.w = fmaxf(acc1.w, 0.0f);
        acc2.x = fmaxf(acc2.x, 0.0f); acc2.y = fmaxf(acc2.y, 0.0f);
        acc2.z = fmaxf(acc2.z, 0.0f); acc2.w = fmaxf(acc2.w, 0.0f);
        acc3.x = fmaxf(acc3.x, 0.0f); acc3.y = fmaxf(acc3.y, 0.0f);
        acc3.z = fmaxf(acc3.z, 0.0f); acc3.w = fmaxf(acc3.w, 0.0f);
    }

    float4* out4 = reinterpret_cast<float4*>(out);
    const size_t n0 = (size_t)(base + 4 * g) * 32 + t;
    out4[n0 + 0 * 32] = acc0;
    out4[n0 + 1 * 32] = acc1;
    out4[n0 + 2 * 32] = acc2;
    out4[n0 + 3 * 32] = acc3;
}

extern "C" void kernel_launch(void* const* d_in, const int* in_sizes, int n_in,
                              void* d_out, int out_size, void* d_ws, size_t ws_size,
                              hipStream_t stream) {
    const float* x    = (const float*)d_in[0];
    const float* ea   = (const float*)d_in[1];
    const float* W1   = (const float*)d_in[2];
    const float* b1   = (const float*)d_in[3];
    const float* W2   = (const float*)d_in[4];
    const float* b2   = (const float*)d_in[5];
    const float* eps  = (const float*)d_in[6];
    const int*   ei   = (const int*)d_in[7];
    float* out = (float*)d_out;

    int* w        = (int*)d_ws;
    int* deg      = w + WS_DEG;
    int* partials = w + WS_PARTIALS;
    int* offs     = w + WS_OFFS;
    int* cursor   = w + WS_CURSOR;
    int* entries  = w + WS_ENTRIES;

    // --- CSR build (all int, ~6 MB ws) ---
    zero_kernel<<<(ZERO_INTS + 255) / 256, 256, 0, stream>>>(w);
    hist_kernel<<<(NE + 255) / 256, 256, 0, stream>>>(ei, deg);
    scan1_kernel<<<391, 256, 0, stream>>>(deg, offs, partials);
    scan2_kernel<<<1, 512, 0, stream>>>(partials);
    finalize_kernel<<<391, 256, 0, stream>>>(offs, partials, cursor);
    fill_kernel<<<(NE + 255) / 256, 256, 0, stream>>>(ei, cursor, entries);

    // --- node pipeline, all in-place in d_out ---
    init_kernel<<<NN * DD / 4 / 256, 256, 0, stream>>>(x, eps, out);
    gather_kernel<<<NN / 8, 256, 0, stream>>>(x, ea, ei, offs, entries, out);
    mlp_kernel<1><<<NN / 32, 256, 0, stream>>>(out, W1, b1, out);
    mlp_kernel<0><<<NN / 32, 256, 0, stream>>>(out, W2, b2, out);
}

// Round 7
// 807.454 us; speedup vs baseline: 3.1468x; 1.1068x over previous
//
#include <hip/hip_runtime.h>

#define NN 100000
#define NE 600000
#define DD 128

// ws layout (int offsets from base):
#define WS_DEG      0         // [100352]
#define WS_PARTIALS 100352    // [512]
#define WS_OFFS     100864    // [100352] (needs NN+1)
#define WS_CURSOR   201216    // [100352]
#define WS_ENTRIES  301568    // int2 [1200000] = 2400000 ints (~10.8 MB total)
#define ZERO_INTS   100864    // deg + partials zeroed every launch

// ---------------------------------------------------------------------------
__global__ __launch_bounds__(256) void zero_kernel(int* __restrict__ w) {
    const int i = blockIdx.x * 256 + threadIdx.x;
    if (i < ZERO_INTS) w[i] = 0;
}

__global__ __launch_bounds__(256) void hist_kernel(const int* __restrict__ ei,
                                                   int* __restrict__ deg) {
    const int e = blockIdx.x * 256 + threadIdx.x;
    if (e >= NE) return;
    atomicAdd(&deg[ei[e]], 1);
    atomicAdd(&deg[ei[NE + e]], 1);
}

__global__ __launch_bounds__(256) void scan1_kernel(const int* __restrict__ deg,
                                                    int* __restrict__ offs,
                                                    int* __restrict__ partials) {
    __shared__ int s[256];
    const int tid = threadIdx.x;
    const int i = blockIdx.x * 256 + tid;
    const int v = deg[i];
    s[tid] = v;
    __syncthreads();
#pragma unroll
    for (int d = 1; d < 256; d <<= 1) {
        const int t = (tid >= d) ? s[tid - d] : 0;
        __syncthreads();
        s[tid] += t;
        __syncthreads();
    }
    offs[i] = s[tid] - v;
    if (tid == 255) partials[blockIdx.x] = s[255];
}

__global__ __launch_bounds__(512) void scan2_kernel(int* __restrict__ partials) {
    __shared__ int s[512];
    const int tid = threadIdx.x;
    const int v = (tid < 391) ? partials[tid] : 0;
    s[tid] = v;
    __syncthreads();
#pragma unroll
    for (int d = 1; d < 512; d <<= 1) {
        const int t = (tid >= d) ? s[tid - d] : 0;
        __syncthreads();
        s[tid] += t;
        __syncthreads();
    }
    if (tid < 391) partials[tid] = s[tid] - v;
}

__global__ __launch_bounds__(256) void finalize_kernel(int* __restrict__ offs,
                                                       const int* __restrict__ partials,
                                                       int* __restrict__ cursor) {
    const int i = blockIdx.x * 256 + threadIdx.x;
    if (i > NN) return;
    const int r = offs[i] + partials[i >> 8];
    offs[i] = r;
    if (i < NN) cursor[i] = r;
}

// entries2[pos] = {edge, other_node}: kills one level of the dependent-load
// chain in gather (entries -> ei -> x becomes entries -> {ea, x} parallel).
__global__ __launch_bounds__(256) void fill_kernel(const int* __restrict__ ei,
                                                   int* __restrict__ cursor,
                                                   int2* __restrict__ entries2) {
    const int e = blockIdx.x * 256 + threadIdx.x;
    if (e >= NE) return;
    const int u = ei[e];
    const int v = ei[NE + e];
    const int p1 = atomicAdd(&cursor[u], 1);
    entries2[p1] = make_int2(e, v);
    const int p2 = atomicAdd(&cursor[v], 1);
    entries2[p2] = make_int2(e, u);
}

__global__ __launch_bounds__(256) void init_kernel(const float* __restrict__ x,
                                                   const float* __restrict__ eps_p,
                                                   float* __restrict__ out) {
    const int i = blockIdx.x * 256 + threadIdx.x;  // 12500 blocks exact
    const float s = 1.0f + eps_p[0];
    float4 v = reinterpret_cast<const float4*>(x)[i];
    v.x *= s; v.y *= s; v.z *= s; v.w *= s;
    reinterpret_cast<float4*>(out)[i] = v;
}

// One 32-lane group per node; 2 edges in flight (4 independent float4 loads
// per iteration) to cover L2/L3 gather latency.
__global__ __launch_bounds__(256) void gather_kernel(const float* __restrict__ x,
                                                     const float* __restrict__ ea,
                                                     const int* __restrict__ offs,
                                                     const int2* __restrict__ entries2,
                                                     float* __restrict__ out) {
    const int node = blockIdx.x * 8 + (threadIdx.x >> 5);  // 12500 blocks exact
    const int t = threadIdx.x & 31;
    const int start = offs[node];
    const int end = offs[node + 1];
    const float4* x4 = reinterpret_cast<const float4*>(x);
    const float4* ea4 = reinterpret_cast<const float4*>(ea);
    float4 acc = {0.0f, 0.0f, 0.0f, 0.0f};
    int j = start;
    for (; j + 1 < end; j += 2) {
        const int2 p0 = entries2[j];
        const int2 p1 = entries2[j + 1];
        const float4 a0 = ea4[(size_t)p0.x * 32 + t];
        const float4 x0 = x4[(size_t)p0.y * 32 + t];
        const float4 a1 = ea4[(size_t)p1.x * 32 + t];
        const float4 x1 = x4[(size_t)p1.y * 32 + t];
        acc.x += fmaxf(x0.x + a0.x, 0.0f) + fmaxf(x1.x + a1.x, 0.0f);
        acc.y += fmaxf(x0.y + a0.y, 0.0f) + fmaxf(x1.y + a1.y, 0.0f);
        acc.z += fmaxf(x0.z + a0.z, 0.0f) + fmaxf(x1.z + a1.z, 0.0f);
        acc.w += fmaxf(x0.w + a0.w, 0.0f) + fmaxf(x1.w + a1.w, 0.0f);
    }
    if (j < end) {
        const int2 p0 = entries2[j];
        const float4 a0 = ea4[(size_t)p0.x * 32 + t];
        const float4 x0 = x4[(size_t)p0.y * 32 + t];
        acc.x += fmaxf(x0.x + a0.x, 0.0f);
        acc.y += fmaxf(x0.y + a0.y, 0.0f);
        acc.z += fmaxf(x0.z + a0.z, 0.0f);
        acc.w += fmaxf(x0.w + a0.w, 0.0f);
    }
    float4* out4 = reinterpret_cast<float4*>(out);
    const size_t oi = (size_t)node * 32 + t;
    float4 o = out4[oi];
    o.x += acc.x; o.y += acc.y; o.z += acc.z; o.w += acc.w;
    out4[oi] = o;
}

// ---------------------------------------------------------------------------
// MLP: persistent blocks. Each block loads W (64 KB LDS) ONCE, then
// grid-strides over 32-node tiles (h staged in 16 KB LDS per tile).
// Amortizes the W prologue that dominated the per-tile-block version.
// 80 KB LDS -> 2 blocks/CU. In-place safe per tile (rows staged before write).
// ---------------------------------------------------------------------------
#define MLP_GRID 512
#define NTILES   (NN / 32)   // 3125

template <int RELU>
__global__ __launch_bounds__(256) void mlp_kernel(const float* __restrict__ in,
                                                  const float* __restrict__ W,
                                                  const float* __restrict__ bias,
                                                  float* __restrict__ out) {
    __shared__ float Wl[DD * DD];    // 64 KB, loaded once
    __shared__ float hl[32 * DD];    // 16 KB, per tile
    const int tid = threadIdx.x;
    float4* Wl4 = reinterpret_cast<float4*>(Wl);
    const float4* W4 = reinterpret_cast<const float4*>(W);
#pragma unroll
    for (int i = 0; i < 16; ++i) Wl4[i * 256 + tid] = W4[i * 256 + tid];

    const int g = tid >> 5;
    const int t = tid & 31;
    const float4 bb = reinterpret_cast<const float4*>(bias)[t];
    float4* hl4 = reinterpret_cast<float4*>(hl);
    const float4* in4 = reinterpret_cast<const float4*>(in);
    float4* out4 = reinterpret_cast<float4*>(out);

    for (int tile = blockIdx.x; tile < NTILES; tile += MLP_GRID) {
        const int base = tile * 32;
        __syncthreads();  // previous tile's hl readers done (also fences W, 1st iter)
#pragma unroll
        for (int i = 0; i < 4; ++i)
            hl4[i * 256 + tid] = in4[(size_t)base * 32 + i * 256 + tid];
        __syncthreads();

        const float4* h0 = reinterpret_cast<const float4*>(hl + (4 * g + 0) * DD);
        const float4* h1 = reinterpret_cast<const float4*>(hl + (4 * g + 1) * DD);
        const float4* h2 = reinterpret_cast<const float4*>(hl + (4 * g + 2) * DD);
        const float4* h3 = reinterpret_cast<const float4*>(hl + (4 * g + 3) * DD);

        float4 acc0 = {0, 0, 0, 0}, acc1 = {0, 0, 0, 0};
        float4 acc2 = {0, 0, 0, 0}, acc3 = {0, 0, 0, 0};

#pragma unroll 8
        for (int kq = 0; kq < 32; ++kq) {
            const float4 ha = h0[kq];
            const float4 hb = h1[kq];
            const float4 hc = h2[kq];
            const float4 hd = h3[kq];
            const float4 w0 = Wl4[(4 * kq + 0) * 32 + t];
            const float4 w1 = Wl4[(4 * kq + 1) * 32 + t];
            const float4 w2 = Wl4[(4 * kq + 2) * 32 + t];
            const float4 w3 = Wl4[(4 * kq + 3) * 32 + t];

#define ACC_STEP(A, H)                                    \
            A.x = fmaf(H.x, w0.x, A.x);                   \
            A.y = fmaf(H.x, w0.y, A.y);                   \
            A.z = fmaf(H.x, w0.z, A.z);                   \
            A.w = fmaf(H.x, w0.w, A.w);                   \
            A.x = fmaf(H.y, w1.x, A.x);                   \
            A.y = fmaf(H.y, w1.y, A.y);                   \
            A.z = fmaf(H.y, w1.z, A.z);                   \
            A.w = fmaf(H.y, w1.w, A.w);                   \
            A.x = fmaf(H.z, w2.x, A.x);                   \
            A.y = fmaf(H.z, w2.y, A.y);                   \
            A.z = fmaf(H.z, w2.z, A.z);                   \
            A.w = fmaf(H.z, w2.w, A.w);                   \
            A.x = fmaf(H.w, w3.x, A.x);                   \
            A.y = fmaf(H.w, w3.y, A.y);                   \
            A.z = fmaf(H.w, w3.z, A.z);                   \
            A.w = fmaf(H.w, w3.w, A.w);
            ACC_STEP(acc0, ha)
            ACC_STEP(acc1, hb)
            ACC_STEP(acc2, hc)
            ACC_STEP(acc3, hd)
#undef ACC_STEP
        }

        acc0.x += bb.x; acc0.y += bb.y; acc0.z += bb.z; acc0.w += bb.w;
        acc1.x += bb.x; acc1.y += bb.y; acc1.z += bb.z; acc1.w += bb.w;
        acc2.x += bb.x; acc2.y += bb.y; acc2.z += bb.z; acc2.w += bb.w;
        acc3.x += bb.x; acc3.y += bb.y; acc3.z += bb.z; acc3.w += bb.w;
        if (RELU) {
            acc0.x = fmaxf(acc0.x, 0.0f); acc0.y = fmaxf(acc0.y, 0.0f);
            acc0.z = fmaxf(acc0.z, 0.0f); acc0.w = fmaxf(acc0.w, 0.0f);
            acc1.x = fmaxf(acc1.x, 0.0f); acc1.y = fmaxf(acc1.y, 0.0f);
            acc1.z = fmaxf(acc1.z, 0.0f); acc1.w = fmaxf(acc1.w, 0.0f);
            acc2.x = fmaxf(acc2.x, 0.0f); acc2.y = fmaxf(acc2.y, 0.0f);
            acc2.z = fmaxf(acc2.z, 0.0f); acc2.w = fmaxf(acc2.w, 0.0f);
            acc3.x = fmaxf(acc3.x, 0.0f); acc3.y = fmaxf(acc3.y, 0.0f);
            acc3.z = fmaxf(acc3.z, 0.0f); acc3.w = fmaxf(acc3.w, 0.0f);
        }

        const size_t n0 = (size_t)(base + 4 * g) * 32 + t;
        out4[n0 + 0 * 32] = acc0;
        out4[n0 + 1 * 32] = acc1;
        out4[n0 + 2 * 32] = acc2;
        out4[n0 + 3 * 32] = acc3;
    }
}

extern "C" void kernel_launch(void* const* d_in, const int* in_sizes, int n_in,
                              void* d_out, int out_size, void* d_ws, size_t ws_size,
                              hipStream_t stream) {
    const float* x    = (const float*)d_in[0];
    const float* ea   = (const float*)d_in[1];
    const float* W1   = (const float*)d_in[2];
    const float* b1   = (const float*)d_in[3];
    const float* W2   = (const float*)d_in[4];
    const float* b2   = (const float*)d_in[5];
    const float* eps  = (const float*)d_in[6];
    const int*   ei   = (const int*)d_in[7];
    float* out = (float*)d_out;

    int*  w        = (int*)d_ws;
    int*  deg      = w + WS_DEG;
    int*  partials = w + WS_PARTIALS;
    int*  offs     = w + WS_OFFS;
    int*  cursor   = w + WS_CURSOR;
    int2* entries2 = (int2*)(w + WS_ENTRIES);

    // --- CSR build ---
    zero_kernel<<<(ZERO_INTS + 255) / 256, 256, 0, stream>>>(w);
    hist_kernel<<<(NE + 255) / 256, 256, 0, stream>>>(ei, deg);
    scan1_kernel<<<391, 256, 0, stream>>>(deg, offs, partials);
    scan2_kernel<<<1, 512, 0, stream>>>(partials);
    finalize_kernel<<<391, 256, 0, stream>>>(offs, partials, cursor);
    fill_kernel<<<(NE + 255) / 256, 256, 0, stream>>>(ei, cursor, entries2);

    // --- node pipeline, in-place in d_out ---
    init_kernel<<<NN * DD / 4 / 256, 256, 0, stream>>>(x, eps, out);
    gather_kernel<<<NN / 8, 256, 0, stream>>>(x, ea, offs, entries2, out);
    mlp_kernel<1><<<MLP_GRID, 256, 0, stream>>>(out, W1, b1, out);
    mlp_kernel<0><<<MLP_GRID, 256, 0, stream>>>(out, W2, b2, out);
}